// Round 1
// 2284.272 us; speedup vs baseline: 1.2550x; 1.2550x over previous
//
#include <hip/hip_runtime.h>
#include <hip/hip_fp16.h>

#define BS 256
#define T 256
#define STEPS 255
#define WV 100
#define INP 64
#define H 256
#define G4 1024
#define VOCAB 600

// ---------------- packed f16 dot2 with f32 accumulate ---------------------
typedef _Float16 f16x2 __attribute__((ext_vector_type(2)));

__device__ __forceinline__ float fdot2(unsigned w, unsigned h, float acc) {
#if defined(__has_builtin) && __has_builtin(__builtin_amdgcn_fdot2)
    return __builtin_amdgcn_fdot2(__builtin_bit_cast(f16x2, w),
                                  __builtin_bit_cast(f16x2, h), acc, false);
#else
    __half2 wv = *(const __half2*)&w;
    __half2 hv = *(const __half2*)&h;
    float2 wf = __half22float2(wv), hf = __half22float2(hv);
    return acc + wf.x * hf.x + wf.y * hf.y;
#endif
}

// ---------------- sort: stable descending by length (jax argsort(-len)) ----
__global__ void k_sort(const int* __restrict__ lens, int* __restrict__ sidx,
                       int* __restrict__ dlen, float* __restrict__ out_dec,
                       float* __restrict__ out_sidx) {
    __shared__ int L[BS];
    int i = threadIdx.x;
    L[i] = lens[i];
    __syncthreads();
    int li = L[i];
    int r = 0;
    for (int j = 0; j < BS; ++j) {
        int lj = L[j];
        r += (lj > li) || (lj == li && j < i);
    }
    sidx[r] = i;
    dlen[r] = li - 1;
    out_sidx[r] = (float)i;
    out_dec[r]  = (float)(li - 1);
}

// ---------------- gather sorted captions to output ------------------------
__global__ void k_gather(const float* __restrict__ cin, const int* __restrict__ sidx,
                         float* __restrict__ cout) {
    int b = blockIdx.x;
    int src = sidx[b];
    const float4* in  = (const float4*)(cin + (size_t)src * T * WV);
    float4* out       = (float4*)(cout + (size_t)b * T * WV);
    for (int i = threadIdx.x; i < T * WV / 4; i += 256) out[i] = in[i];
}

// ---------------- W_comb = w_ih @ W_emb^T  [1024 x 100] -------------------
__global__ void k_wcomb(const float* __restrict__ w_ih, const float* __restrict__ W_emb,
                        float* __restrict__ Wc) {
    int idx = blockIdx.x * 256 + threadIdx.x;   // 102400 threads
    int r = idx / WV, cc = idx % WV;
    float acc = 0.f;
    for (int k = 0; k < INP; ++k) acc += w_ih[r * INP + k] * W_emb[k * WV + cc];
    Wc[idx] = acc;
}

// ---------------- b_comb = b_ih + b_hh + w_ih @ b_emb ---------------------
__global__ void k_bcomb(const float* __restrict__ w_ih, const float* __restrict__ b_ih,
                        const float* __restrict__ b_hh, const float* __restrict__ b_emb,
                        float* __restrict__ bc) {
    int r = blockIdx.x * 256 + threadIdx.x;     // 1024 threads
    float acc = b_ih[r] + b_hh[r];
    for (int k = 0; k < INP; ++k) acc += w_ih[r * INP + k] * b_emb[k];
    bc[r] = acc;
}

// ---------------- pack w_hh -> fp16, k-major transposed -------------------
// wT[k2*1024 + r] = half2(w_hh[r][2k2], w_hh[r][2k2+1])
__global__ void k_packw(const float* __restrict__ w_hh, __half2* __restrict__ wT) {
    int idx = blockIdx.x * 256 + threadIdx.x;   // 131072 threads
    int k2 = idx >> 10, r = idx & 1023;
    wT[(size_t)k2 * G4 + r] =
        __floats2half2_rn(w_hh[(size_t)r * H + 2 * k2], w_hh[(size_t)r * H + 2 * k2 + 1]);
}

// ---------------- h0 = enc@W_h^T + b_h ; c0 = enc@W_c^T + b_c -------------
__global__ void k_inithc(const float* __restrict__ enc, const int* __restrict__ sidx,
                         const float* __restrict__ W_h, const float* __restrict__ b_h,
                         const float* __restrict__ W_c, const float* __restrict__ b_c,
                         float* __restrict__ h_st, float* __restrict__ c_st) {
    int b = blockIdx.x, j = threadIdx.x;
    __shared__ __align__(16) float e[INP];
    int src = sidx[b];
    if (j < INP) e[j] = enc[src * INP + j];
    __syncthreads();
    const float4* e4  = (const float4*)e;
    const float4* wh4 = (const float4*)(W_h + (size_t)j * INP);
    const float4* wc4 = (const float4*)(W_c + (size_t)j * INP);
    float ah = b_h[j], ac = b_c[j];
    #pragma unroll
    for (int k4 = 0; k4 < INP / 4; ++k4) {
        float4 ev = e4[k4];
        float4 wh = wh4[k4];
        float4 wc = wc4[k4];
        ah += ev.x * wh.x + ev.y * wh.y + ev.z * wh.z + ev.w * wh.w;
        ac += ev.x * wc.x + ev.y * wc.y + ev.z * wc.z + ev.w * wc.w;
    }
    h_st[b * H + j] = ah;
    c_st[b * H + j] = ac;
}

// ---------------- xg[b,ct,:] = caps_sorted[b,t,:] @ W_comb^T + b_comb -----
__global__ void k_xg(const float* __restrict__ caps, const float* __restrict__ Wc,
                     const float* __restrict__ bc, const int* __restrict__ dlen,
                     float* __restrict__ xg, int t0, int Cc) {
    int b = blockIdx.y;
    int ct0 = blockIdx.x * 16;
    if (t0 + ct0 >= dlen[b]) return;   // rows never consumed by the LSTM
    __shared__ __align__(16) float4 cs4[16][WV / 4];   // 16 timesteps x 100
    float* cs = (float*)cs4;
    for (int i = threadIdx.x; i < 16 * WV; i += 256) {
        int rr = i / WV, k = i % WV;
        int t = t0 + ct0 + rr;
        cs[rr * WV + k] = (t < T && ct0 + rr < Cc) ? caps[((size_t)b * T + t) * WV + k] : 0.f;
    }
    __syncthreads();
    int nrow = Cc - ct0; if (nrow > 16) nrow = 16;
    for (int rq = 0; rq < 4; ++rq) {
        int r = threadIdx.x + rq * 256;
        float acc[16];
        float bv = bc[r];
        #pragma unroll
        for (int rr = 0; rr < 16; ++rr) acc[rr] = bv;
        const float4* wr = (const float4*)(Wc + (size_t)r * WV);
        for (int k4 = 0; k4 < WV / 4; ++k4) {
            float4 w = wr[k4];
            #pragma unroll
            for (int rr = 0; rr < 16; ++rr) {
                float4 av = cs4[rr][k4];
                acc[rr] += av.x * w.x + av.y * w.y + av.z * w.z + av.w * w.w;
            }
        }
        for (int rr = 0; rr < nrow; ++rr)
            xg[((size_t)b * Cc + ct0 + rr) * G4 + r] = acc[rr];
    }
}

// ---------------- recurrent LSTM core: one block per batch row ------------
// 512 threads, ALL w_hh weights on-chip:
//   rows 0..511 (i,f): thread t holds row t in regs      (128 half2 VGPRs)
//   rows 512..767 (g): pair (j, j+256) split K-halves    ( 64 half2 VGPRs)
//   rows 768..1023(o): LDS, k-major [k2][row] = 128 KB   (conflict-free b32)
// h broadcast from LDS as hi/lo f16 split (error ~= f32-h path).
#define LSTM_SMEM (131072 + 3 * 512 * 4 + 2 * 256 * 2)   // 138240 B

__global__ __launch_bounds__(512, 2) void k_lstm(const __half2* __restrict__ wT,
        const float* __restrict__ xg, const int* __restrict__ dlen,
        float* __restrict__ h_st, float* __restrict__ c_st,
        __half* __restrict__ hck, int t0, int Cc) {
    extern __shared__ __align__(16) char smem[];
    unsigned* o_lds = (unsigned*)smem;                  // [128][256] k-major half2
    float* sA = (float*)(smem + 131072);                // 512: i/f gate rows
    float* sG = sA + 512;                               // 512: g partials
    float* sO = sG + 512;                               // 512: o partials
    __half* hhi = (__half*)(sO + 512);                  // 256 (16B aligned)
    __half* hlo = hhi + 256;                            // 256

    int b = blockIdx.x, tid = threadIdx.x;
    int steps_b = dlen[b];
    if (t0 >= steps_b) return;

    const unsigned* wTu = (const unsigned*)wT;
    int r  = tid & 255;
    int kh = tid >> 8;            // which K-half this thread owns for g/o

    // ---- preload all recurrent weights on-chip (once per launch) ----
    unsigned wo[128];             // own row `tid` (i for tid<256, f else)
    #pragma unroll
    for (int k2 = 0; k2 < 128; ++k2) wo[k2] = wTu[k2 * G4 + tid];
    unsigned wg[64];              // g-row 512+r, K-half kh
    #pragma unroll
    for (int i = 0; i < 64; ++i) wg[i] = wTu[(kh * 64 + i) * G4 + 512 + r];
    for (int i = tid; i < 128 * 256; i += 512) {        // o rows -> LDS k-major
        int kk = i >> 8, rr = i & 255;
        o_lds[i] = wTu[kk * G4 + 768 + rr];
    }

    float c = 0.f, hcur = 0.f;
    if (tid < H) {
        hcur = h_st[b * H + tid];
        c    = c_st[b * H + tid];
        __half hh16 = __float2half(hcur);
        hhi[tid] = hh16;
        hlo[tid] = __float2half(hcur - __half2float(hh16));
    }
    __syncthreads();

    const uint4* hhi4 = (const uint4*)hhi;   // 4 half2 per read (broadcast)
    const uint4* hlo4 = (const uint4*)hlo;
    int tend = t0 + Cc; if (tend > steps_b) tend = steps_b;
    const float* xgp = xg + (size_t)b * Cc * G4;
    __half* hckp = hck + (size_t)b * Cc * H;

    for (int t = t0; t < tend; ++t) {
        float xa = xgp[tid];                 // consumed after dot phase
        float xgg = 0.f, xgo = 0.f;
        if (tid < H) { xgg = xgp[512 + tid]; xgo = xgp[768 + tid]; }

        // ---- own i/f row: full K, hi+lo dots, 8 independent chains ----
        float ah0 = 0.f, ah1 = 0.f, ah2 = 0.f, ah3 = 0.f;
        float al0 = 0.f, al1 = 0.f, al2 = 0.f, al3 = 0.f;
        #pragma unroll
        for (int c8 = 0; c8 < 32; ++c8) {
            uint4 hh = hhi4[c8];
            uint4 hl = hlo4[c8];
            ah0 = fdot2(wo[4 * c8 + 0], hh.x, ah0);
            ah1 = fdot2(wo[4 * c8 + 1], hh.y, ah1);
            ah2 = fdot2(wo[4 * c8 + 2], hh.z, ah2);
            ah3 = fdot2(wo[4 * c8 + 3], hh.w, ah3);
            al0 = fdot2(wo[4 * c8 + 0], hl.x, al0);
            al1 = fdot2(wo[4 * c8 + 1], hl.y, al1);
            al2 = fdot2(wo[4 * c8 + 2], hl.z, al2);
            al3 = fdot2(wo[4 * c8 + 3], hl.w, al3);
        }
        float A = ((ah0 + ah1) + (ah2 + ah3)) + ((al0 + al1) + (al2 + al3)) + xa;

        // ---- g-row (regs) + o-row (LDS) partials over my K-half ----
        float gh0 = 0.f, gh1 = 0.f, gl0 = 0.f, gl1 = 0.f;
        float oh0 = 0.f, oh1 = 0.f, ol0 = 0.f, ol1 = 0.f;
        #pragma unroll
        for (int i = 0; i < 16; ++i) {
            int cg = kh * 16 + i;
            uint4 hh = hhi4[cg];
            uint4 hl = hlo4[cg];
            int kbase = kh * 64 + 4 * i;
            unsigned ow0 = o_lds[(kbase + 0) * 256 + r];
            unsigned ow1 = o_lds[(kbase + 1) * 256 + r];
            unsigned ow2 = o_lds[(kbase + 2) * 256 + r];
            unsigned ow3 = o_lds[(kbase + 3) * 256 + r];
            gh0 = fdot2(wg[4 * i + 0], hh.x, gh0);
            gh1 = fdot2(wg[4 * i + 1], hh.y, gh1);
            gh0 = fdot2(wg[4 * i + 2], hh.z, gh0);
            gh1 = fdot2(wg[4 * i + 3], hh.w, gh1);
            gl0 = fdot2(wg[4 * i + 0], hl.x, gl0);
            gl1 = fdot2(wg[4 * i + 1], hl.y, gl1);
            gl0 = fdot2(wg[4 * i + 2], hl.z, gl0);
            gl1 = fdot2(wg[4 * i + 3], hl.w, gl1);
            oh0 = fdot2(ow0, hh.x, oh0);
            oh1 = fdot2(ow1, hh.y, oh1);
            oh0 = fdot2(ow2, hh.z, oh0);
            oh1 = fdot2(ow3, hh.w, oh1);
            ol0 = fdot2(ow0, hl.x, ol0);
            ol1 = fdot2(ow1, hl.y, ol1);
            ol0 = fdot2(ow2, hl.z, ol0);
            ol1 = fdot2(ow3, hl.w, ol1);
        }
        float Gp = (gh0 + gh1) + (gl0 + gl1);
        float Op = (oh0 + oh1) + (ol0 + ol1);

        sA[tid] = A; sG[tid] = Gp; sO[tid] = Op;
        __syncthreads();
        if (tid < H) {
            float iv = sA[tid];
            float fv = sA[H + tid];
            float gv = sG[tid] + sG[H + tid] + xgg;
            float ov = sO[tid] + sO[H + tid] + xgo;
            iv = 1.f / (1.f + __expf(-iv));
            fv = 1.f / (1.f + __expf(-fv));
            gv = tanhf(gv);
            ov = 1.f / (1.f + __expf(-ov));
            c = fv * c + iv * gv;
            float nh = ov * tanhf(c);
            hcur = nh;
            __half hh16 = __float2half(nh);
            hckp[tid] = hh16;
            hhi[tid] = hh16;
            hlo[tid] = __float2half(nh - __half2float(hh16));
        }
        __syncthreads();
        xgp += G4;
        hckp += H;
    }
    if (tid < H) { h_st[b * H + tid] = hcur; c_st[b * H + tid] = c; }
}

// ---------------- logits = h @ W_out^T + b_out, masked with -1 ------------
__global__ void k_logits(const __half* __restrict__ hck, const float* __restrict__ Wo,
                         const float* __restrict__ bo, const int* __restrict__ dlen,
                         float* __restrict__ pred, int t0, int Cc) {
    int b = blockIdx.y;
    int ct0 = blockIdx.x * 16;
    if (ct0 >= Cc) return;
    int steps_b = dlen[b];
    int nrow = Cc - ct0; if (nrow > 16) nrow = 16;
    if (t0 + ct0 >= steps_b) {   // whole tile inactive: write -1
        for (int rr = 0; rr < nrow; ++rr) {
            int t = t0 + ct0 + rr;
            if (t >= STEPS) break;
            float* pr = pred + ((size_t)b * STEPS + t) * VOCAB;
            for (int cidx = threadIdx.x; cidx < VOCAB; cidx += 256) pr[cidx] = -1.f;
        }
        return;
    }
    __shared__ __align__(16) float4 a4[16][H / 4];
    float* a = (float*)a4;
    for (int i = threadIdx.x; i < 16 * H; i += 256) {
        int rr = i >> 8, k = i & 255;
        float v = (rr < nrow) ? __half2float(hck[((size_t)b * Cc + ct0 + rr) * H + k]) : 0.f;
        a[rr * H + k] = v;
    }
    __syncthreads();
    for (int cidx = threadIdx.x; cidx < VOCAB; cidx += 256) {
        const float4* wr = (const float4*)(Wo + (size_t)cidx * H);
        float acc[16];
        float bv = bo[cidx];
        #pragma unroll
        for (int rr = 0; rr < 16; ++rr) acc[rr] = bv;
        for (int k4 = 0; k4 < H / 4; ++k4) {
            float4 w = wr[k4];
            #pragma unroll
            for (int rr = 0; rr < 16; ++rr) {
                float4 av = a4[rr][k4];
                acc[rr] += av.x * w.x + av.y * w.y + av.z * w.z + av.w * w.w;
            }
        }
        for (int rr = 0; rr < nrow; ++rr) {
            int t = t0 + ct0 + rr;
            if (t >= STEPS) break;
            pred[((size_t)b * STEPS + t) * VOCAB + cidx] = (t < steps_b) ? acc[rr] : -1.f;
        }
    }
}

extern "C" void kernel_launch(void* const* d_in, const int* in_sizes, int n_in,
                              void* d_out, int out_size, void* d_ws, size_t ws_size,
                              hipStream_t stream) {
    const float* enc   = (const float*)d_in[0];
    const float* caps  = (const float*)d_in[1];
    const float* w_ih  = (const float*)d_in[2];
    const float* w_hh  = (const float*)d_in[3];
    const float* b_ih  = (const float*)d_in[4];
    const float* b_hh  = (const float*)d_in[5];
    const float* W_out = (const float*)d_in[6];
    const float* b_out = (const float*)d_in[7];
    const float* W_emb = (const float*)d_in[8];
    const float* b_emb = (const float*)d_in[9];
    const float* W_h   = (const float*)d_in[10];
    const float* b_h   = (const float*)d_in[11];
    const float* W_c   = (const float*)d_in[12];
    const float* b_c   = (const float*)d_in[13];
    const int*   lens  = (const int*)d_in[14];

    float* out_pred = (float*)d_out;
    float* out_caps = out_pred + (size_t)BS * STEPS * VOCAB;
    float* out_dec  = out_caps + (size_t)BS * T * WV;
    float* out_sidx = out_dec + BS;

    char* w = (char*)d_ws;
    size_t off = 0;
    auto take = [&](size_t bytes) -> char* {
        char* p = w + off;
        off += (bytes + 255) & ~(size_t)255;
        return p;
    };
    int*     sidx = (int*)take(BS * 4);
    int*     dlen = (int*)take(BS * 4);
    float*   Wc   = (float*)take((size_t)G4 * WV * 4);
    float*   bc   = (float*)take(G4 * 4);
    float*   h_st = (float*)take((size_t)BS * H * 4);
    float*   c_st = (float*)take((size_t)BS * H * 4);
    __half2* wT   = (__half2*)take((size_t)(H / 2) * G4 * 4);

    size_t rem = (ws_size > off) ? (ws_size - off) : 0;
    size_t per_step = (size_t)BS * G4 * 4 + (size_t)BS * H * 2 + 1024;
    int C = (int)(rem / per_step);
    if (C < 1) C = 1;
    if (C > STEPS) C = STEPS;
    float*  xg  = (float*)take((size_t)BS * C * G4 * 4);
    __half* hck = (__half*)take((size_t)BS * C * H * 2);

    // allow 138 KB dynamic LDS for the recurrent kernel (host-side, capture-safe)
    (void)hipFuncSetAttribute((const void*)k_lstm,
                              hipFuncAttributeMaxDynamicSharedMemorySize, LSTM_SMEM);

    k_sort<<<1, 256, 0, stream>>>(lens, sidx, dlen, out_dec, out_sidx);
    k_gather<<<BS, 256, 0, stream>>>(caps, sidx, out_caps);
    k_wcomb<<<G4 * WV / 256, 256, 0, stream>>>(w_ih, W_emb, Wc);
    k_bcomb<<<G4 / 256, 256, 0, stream>>>(w_ih, b_ih, b_hh, b_emb, bc);
    k_packw<<<(H / 2) * G4 / 256, 256, 0, stream>>>(w_hh, wT);
    k_inithc<<<BS, 256, 0, stream>>>(enc, sidx, W_h, b_h, W_c, b_c, h_st, c_st);

    for (int t0 = 0; t0 < STEPS; t0 += C) {
        int Cc = STEPS - t0; if (Cc > C) Cc = C;
        dim3 g((Cc + 15) / 16, BS);
        k_xg<<<g, 256, 0, stream>>>(out_caps, Wc, bc, dlen, xg, t0, Cc);
        k_lstm<<<BS, 512, LSTM_SMEM, stream>>>(wT, xg, dlen, h_st, c_st, hck, t0, Cc);
        k_logits<<<g, 256, 0, stream>>>(hck, W_out, b_out, dlen, out_pred, t0, Cc);
    }
}

// Round 2
// 2124.286 us; speedup vs baseline: 1.3496x; 1.0753x over previous
//
#include <hip/hip_runtime.h>
#include <hip/hip_fp16.h>

#define BS 256
#define T 256
#define STEPS 255
#define WV 100
#define INP 64
#define H 256
#define G4 1024
#define VOCAB 600

// ---------------- packed f16 dot2 with f32 accumulate ---------------------
typedef _Float16 f16x2 __attribute__((ext_vector_type(2)));

__device__ __forceinline__ float fdot2(unsigned w, unsigned h, float acc) {
#if defined(__has_builtin) && __has_builtin(__builtin_amdgcn_fdot2)
    return __builtin_amdgcn_fdot2(__builtin_bit_cast(f16x2, w),
                                  __builtin_bit_cast(f16x2, h), acc, false);
#else
    __half2 wv = *(const __half2*)&w;
    __half2 hv = *(const __half2*)&h;
    float2 wf = __half22float2(wv), hf = __half22float2(hv);
    return acc + wf.x * hf.x + wf.y * hf.y;
#endif
}

// ---------------- sort: stable descending by length (jax argsort(-len)) ----
__global__ void k_sort(const int* __restrict__ lens, int* __restrict__ sidx,
                       int* __restrict__ dlen, float* __restrict__ out_dec,
                       float* __restrict__ out_sidx) {
    __shared__ int L[BS];
    int i = threadIdx.x;
    L[i] = lens[i];
    __syncthreads();
    int li = L[i];
    int r = 0;
    for (int j = 0; j < BS; ++j) {
        int lj = L[j];
        r += (lj > li) || (lj == li && j < i);
    }
    sidx[r] = i;
    dlen[r] = li - 1;
    out_sidx[r] = (float)i;
    out_dec[r]  = (float)(li - 1);
}

// ---------------- gather sorted captions to output ------------------------
__global__ void k_gather(const float* __restrict__ cin, const int* __restrict__ sidx,
                         float* __restrict__ cout) {
    int b = blockIdx.x;
    int src = sidx[b];
    const float4* in  = (const float4*)(cin + (size_t)src * T * WV);
    float4* out       = (float4*)(cout + (size_t)b * T * WV);
    for (int i = threadIdx.x; i < T * WV / 4; i += 256) out[i] = in[i];
}

// ---------------- W_comb = w_ih @ W_emb^T  [1024 x 100] -------------------
__global__ void k_wcomb(const float* __restrict__ w_ih, const float* __restrict__ W_emb,
                        float* __restrict__ Wc) {
    int idx = blockIdx.x * 256 + threadIdx.x;   // 102400 threads
    int r = idx / WV, cc = idx % WV;
    float acc = 0.f;
    for (int k = 0; k < INP; ++k) acc += w_ih[r * INP + k] * W_emb[k * WV + cc];
    Wc[idx] = acc;
}

// ---------------- b_comb = b_ih + b_hh + w_ih @ b_emb ---------------------
__global__ void k_bcomb(const float* __restrict__ w_ih, const float* __restrict__ b_ih,
                        const float* __restrict__ b_hh, const float* __restrict__ b_emb,
                        float* __restrict__ bc) {
    int r = blockIdx.x * 256 + threadIdx.x;     // 1024 threads
    float acc = b_ih[r] + b_hh[r];
    for (int k = 0; k < INP; ++k) acc += w_ih[r * INP + k] * b_emb[k];
    bc[r] = acc;
}

// ---------------- pack w_hh -> fp16, k-major transposed -------------------
// wT[k2*1024 + r] = half2(w_hh[r][2k2], w_hh[r][2k2+1])
__global__ void k_packw(const float* __restrict__ w_hh, __half2* __restrict__ wT) {
    int idx = blockIdx.x * 256 + threadIdx.x;   // 131072 threads
    int k2 = idx >> 10, r = idx & 1023;
    wT[(size_t)k2 * G4 + r] =
        __floats2half2_rn(w_hh[(size_t)r * H + 2 * k2], w_hh[(size_t)r * H + 2 * k2 + 1]);
}

// ---------------- h0 = enc@W_h^T + b_h ; c0 = enc@W_c^T + b_c -------------
__global__ void k_inithc(const float* __restrict__ enc, const int* __restrict__ sidx,
                         const float* __restrict__ W_h, const float* __restrict__ b_h,
                         const float* __restrict__ W_c, const float* __restrict__ b_c,
                         float* __restrict__ h_st, float* __restrict__ c_st) {
    int b = blockIdx.x, j = threadIdx.x;
    __shared__ __align__(16) float e[INP];
    int src = sidx[b];
    if (j < INP) e[j] = enc[src * INP + j];
    __syncthreads();
    const float4* e4  = (const float4*)e;
    const float4* wh4 = (const float4*)(W_h + (size_t)j * INP);
    const float4* wc4 = (const float4*)(W_c + (size_t)j * INP);
    float ah = b_h[j], ac = b_c[j];
    #pragma unroll
    for (int k4 = 0; k4 < INP / 4; ++k4) {
        float4 ev = e4[k4];
        float4 wh = wh4[k4];
        float4 wc = wc4[k4];
        ah += ev.x * wh.x + ev.y * wh.y + ev.z * wh.z + ev.w * wh.w;
        ac += ev.x * wc.x + ev.y * wc.y + ev.z * wc.z + ev.w * wc.w;
    }
    h_st[b * H + j] = ah;
    c_st[b * H + j] = ac;
}

// ---------------- xg[b,ct,:] = caps_sorted[b,t,:] @ W_comb^T + b_comb -----
__global__ void k_xg(const float* __restrict__ caps, const float* __restrict__ Wc,
                     const float* __restrict__ bc, const int* __restrict__ dlen,
                     float* __restrict__ xg, int t0, int Cc) {
    int b = blockIdx.y;
    int ct0 = blockIdx.x * 16;
    if (t0 + ct0 >= dlen[b]) return;   // rows never consumed by the LSTM
    __shared__ __align__(16) float4 cs4[16][WV / 4];   // 16 timesteps x 100
    float* cs = (float*)cs4;
    for (int i = threadIdx.x; i < 16 * WV; i += 256) {
        int rr = i / WV, k = i % WV;
        int t = t0 + ct0 + rr;
        cs[rr * WV + k] = (t < T && ct0 + rr < Cc) ? caps[((size_t)b * T + t) * WV + k] : 0.f;
    }
    __syncthreads();
    int nrow = Cc - ct0; if (nrow > 16) nrow = 16;
    for (int rq = 0; rq < 4; ++rq) {
        int r = threadIdx.x + rq * 256;
        float acc[16];
        float bv = bc[r];
        #pragma unroll
        for (int rr = 0; rr < 16; ++rr) acc[rr] = bv;
        const float4* wr = (const float4*)(Wc + (size_t)r * WV);
        for (int k4 = 0; k4 < WV / 4; ++k4) {
            float4 w = wr[k4];
            #pragma unroll
            for (int rr = 0; rr < 16; ++rr) {
                float4 av = cs4[rr][k4];
                acc[rr] += av.x * w.x + av.y * w.y + av.z * w.z + av.w * w.w;
            }
        }
        for (int rr = 0; rr < nrow; ++rr)
            xg[((size_t)b * Cc + ct0 + rr) * G4 + r] = acc[rr];
    }
}

// ---------------- recurrent LSTM core: one block per batch row ------------
// 512 threads, ALL w_hh weights on-chip:
//   rows 0..511 (i,f): thread t holds row t in regs      (128 half2 VGPRs)
//   rows 512..767 (g): pair (j, j+256) split K-halves    ( 64 half2 VGPRs)
//   rows 768..1023(o): LDS, k-major [k2][row] = 128 KB   (conflict-free b32)
// h broadcast from LDS as hi/lo f16 split (error ~= f32-h path).
// launch_bounds(512, 1): VGPR cap 512 so the 192 weight dwords stay
// RESIDENT (with (512,2) the allocator clamped to 128 and re-fetched
// weights from L2 every step -> 11.8k cy/step).
#define LSTM_SMEM (131072 + 3 * 512 * 4 + 2 * 256 * 2)   // 138240 B

__global__ __launch_bounds__(512, 1) void k_lstm(const __half2* __restrict__ wT,
        const float* __restrict__ xg, const int* __restrict__ dlen,
        float* __restrict__ h_st, float* __restrict__ c_st,
        __half* __restrict__ hck, int t0, int Cc) {
    extern __shared__ __align__(16) char smem[];
    unsigned* o_lds = (unsigned*)smem;                  // [128][256] k-major half2
    float* sA = (float*)(smem + 131072);                // 512: i/f sigmoids
    float* sG = sA + 512;                               // 512: g partials
    float* sO = sG + 512;                               // 512: o partials
    __half* hhi = (__half*)(sO + 512);                  // 256 (16B aligned)
    __half* hlo = hhi + 256;                            // 256

    int b = blockIdx.x, tid = threadIdx.x;
    int steps_b = dlen[b];
    if (t0 >= steps_b) return;

    const unsigned* wTu = (const unsigned*)wT;
    int r  = tid & 255;
    int kh = tid >> 8;            // which K-half this thread owns for g/o

    // ---- preload all recurrent weights on-chip (once per launch) ----
    unsigned wo[128];             // own row `tid` (i for tid<256, f else)
    #pragma unroll
    for (int k2 = 0; k2 < 128; ++k2) wo[k2] = wTu[k2 * G4 + tid];
    unsigned wg[64];              // g-row 512+r, K-half kh
    #pragma unroll
    for (int i = 0; i < 64; ++i) wg[i] = wTu[(kh * 64 + i) * G4 + 512 + r];
    for (int i = tid; i < 128 * 256; i += 512) {        // o rows -> LDS k-major
        int kk = i >> 8, rr = i & 255;
        o_lds[i] = wTu[kk * G4 + 768 + rr];
    }

    float c = 0.f, hcur = 0.f;
    if (tid < H) {
        hcur = h_st[b * H + tid];
        c    = c_st[b * H + tid];
        __half hh16 = __float2half(hcur);
        hhi[tid] = hh16;
        hlo[tid] = __float2half(hcur - __half2float(hh16));
    }
    __syncthreads();

    const uint4* hhi4 = (const uint4*)hhi;   // 4 half2 per read (broadcast)
    const uint4* hlo4 = (const uint4*)hlo;
    int tend = t0 + Cc; if (tend > steps_b) tend = steps_b;
    const float* xgp = xg + (size_t)b * Cc * G4;
    __half* hckp = hck + (size_t)b * Cc * H;

    for (int t = t0; t < tend; ++t) {
        float xa = xgp[tid];                 // consumed after dot phase
        float xgg = 0.f, xgo = 0.f;
        if (tid < H) { xgg = xgp[512 + tid]; xgo = xgp[768 + tid]; }

        // ---- own i/f row: full K, hi+lo dots, 8 independent chains ----
        float ah0 = 0.f, ah1 = 0.f, ah2 = 0.f, ah3 = 0.f;
        float al0 = 0.f, al1 = 0.f, al2 = 0.f, al3 = 0.f;
        #pragma unroll
        for (int c8 = 0; c8 < 32; ++c8) {
            uint4 hh = hhi4[c8];
            uint4 hl = hlo4[c8];
            ah0 = fdot2(wo[4 * c8 + 0], hh.x, ah0);
            ah1 = fdot2(wo[4 * c8 + 1], hh.y, ah1);
            ah2 = fdot2(wo[4 * c8 + 2], hh.z, ah2);
            ah3 = fdot2(wo[4 * c8 + 3], hh.w, ah3);
            al0 = fdot2(wo[4 * c8 + 0], hl.x, al0);
            al1 = fdot2(wo[4 * c8 + 1], hl.y, al1);
            al2 = fdot2(wo[4 * c8 + 2], hl.z, al2);
            al3 = fdot2(wo[4 * c8 + 3], hl.w, al3);
        }
        float A = ((ah0 + ah1) + (ah2 + ah3)) + ((al0 + al1) + (al2 + al3)) + xa;
        // i/f are both sigmoid: apply on the owner thread, pre-barrier,
        // so the serial epilogue tail has 2 fewer transcendental chains.
        float Asig = 1.f / (1.f + __expf(-A));

        // ---- g-row (regs) + o-row (LDS) partials over my K-half ----
        float gh0 = 0.f, gh1 = 0.f, gl0 = 0.f, gl1 = 0.f;
        float oh0 = 0.f, oh1 = 0.f, ol0 = 0.f, ol1 = 0.f;
        #pragma unroll
        for (int i = 0; i < 16; ++i) {
            int cg = kh * 16 + i;
            uint4 hh = hhi4[cg];
            uint4 hl = hlo4[cg];
            int kbase = kh * 64 + 4 * i;
            unsigned ow0 = o_lds[(kbase + 0) * 256 + r];
            unsigned ow1 = o_lds[(kbase + 1) * 256 + r];
            unsigned ow2 = o_lds[(kbase + 2) * 256 + r];
            unsigned ow3 = o_lds[(kbase + 3) * 256 + r];
            gh0 = fdot2(wg[4 * i + 0], hh.x, gh0);
            gh1 = fdot2(wg[4 * i + 1], hh.y, gh1);
            gh0 = fdot2(wg[4 * i + 2], hh.z, gh0);
            gh1 = fdot2(wg[4 * i + 3], hh.w, gh1);
            gl0 = fdot2(wg[4 * i + 0], hl.x, gl0);
            gl1 = fdot2(wg[4 * i + 1], hl.y, gl1);
            gl0 = fdot2(wg[4 * i + 2], hl.z, gl0);
            gl1 = fdot2(wg[4 * i + 3], hl.w, gl1);
            oh0 = fdot2(ow0, hh.x, oh0);
            oh1 = fdot2(ow1, hh.y, oh1);
            oh0 = fdot2(ow2, hh.z, oh0);
            oh1 = fdot2(ow3, hh.w, oh1);
            ol0 = fdot2(ow0, hl.x, ol0);
            ol1 = fdot2(ow1, hl.y, ol1);
            ol0 = fdot2(ow2, hl.z, ol0);
            ol1 = fdot2(ow3, hl.w, ol1);
        }
        float Gp = (gh0 + gh1) + (gl0 + gl1);
        float Op = (oh0 + oh1) + (ol0 + ol1);

        sA[tid] = Asig; sG[tid] = Gp; sO[tid] = Op;
        __syncthreads();
        if (tid < H) {
            float iv = sA[tid];
            float fv = sA[H + tid];
            float gv = tanhf(sG[tid] + sG[H + tid] + xgg);
            float ov = 1.f / (1.f + __expf(-(sO[tid] + sO[H + tid] + xgo)));
            c = fv * c + iv * gv;
            float nh = ov * tanhf(c);
            hcur = nh;
            __half hh16 = __float2half(nh);
            hckp[tid] = hh16;
            hhi[tid] = hh16;
            hlo[tid] = __float2half(nh - __half2float(hh16));
        }
        __syncthreads();
        xgp += G4;
        hckp += H;
    }
    if (tid < H) { h_st[b * H + tid] = hcur; c_st[b * H + tid] = c; }
}

// ---------------- logits = h @ W_out^T + b_out, masked with -1 ------------
__global__ void k_logits(const __half* __restrict__ hck, const float* __restrict__ Wo,
                         const float* __restrict__ bo, const int* __restrict__ dlen,
                         float* __restrict__ pred, int t0, int Cc) {
    int b = blockIdx.y;
    int ct0 = blockIdx.x * 16;
    if (ct0 >= Cc) return;
    int steps_b = dlen[b];
    int nrow = Cc - ct0; if (nrow > 16) nrow = 16;
    if (t0 + ct0 >= steps_b) {   // whole tile inactive: write -1
        for (int rr = 0; rr < nrow; ++rr) {
            int t = t0 + ct0 + rr;
            if (t >= STEPS) break;
            float* pr = pred + ((size_t)b * STEPS + t) * VOCAB;
            for (int cidx = threadIdx.x; cidx < VOCAB; cidx += 256) pr[cidx] = -1.f;
        }
        return;
    }
    __shared__ __align__(16) float4 a4[16][H / 4];
    float* a = (float*)a4;
    for (int i = threadIdx.x; i < 16 * H; i += 256) {
        int rr = i >> 8, k = i & 255;
        float v = (rr < nrow) ? __half2float(hck[((size_t)b * Cc + ct0 + rr) * H + k]) : 0.f;
        a[rr * H + k] = v;
    }
    __syncthreads();
    for (int cidx = threadIdx.x; cidx < VOCAB; cidx += 256) {
        const float4* wr = (const float4*)(Wo + (size_t)cidx * H);
        float acc[16];
        float bv = bo[cidx];
        #pragma unroll
        for (int rr = 0; rr < 16; ++rr) acc[rr] = bv;
        for (int k4 = 0; k4 < H / 4; ++k4) {
            float4 w = wr[k4];
            #pragma unroll
            for (int rr = 0; rr < 16; ++rr) {
                float4 av = a4[rr][k4];
                acc[rr] += av.x * w.x + av.y * w.y + av.z * w.z + av.w * w.w;
            }
        }
        for (int rr = 0; rr < nrow; ++rr) {
            int t = t0 + ct0 + rr;
            if (t >= STEPS) break;
            pred[((size_t)b * STEPS + t) * VOCAB + cidx] = (t < steps_b) ? acc[rr] : -1.f;
        }
    }
}

extern "C" void kernel_launch(void* const* d_in, const int* in_sizes, int n_in,
                              void* d_out, int out_size, void* d_ws, size_t ws_size,
                              hipStream_t stream) {
    const float* enc   = (const float*)d_in[0];
    const float* caps  = (const float*)d_in[1];
    const float* w_ih  = (const float*)d_in[2];
    const float* w_hh  = (const float*)d_in[3];
    const float* b_ih  = (const float*)d_in[4];
    const float* b_hh  = (const float*)d_in[5];
    const float* W_out = (const float*)d_in[6];
    const float* b_out = (const float*)d_in[7];
    const float* W_emb = (const float*)d_in[8];
    const float* b_emb = (const float*)d_in[9];
    const float* W_h   = (const float*)d_in[10];
    const float* b_h   = (const float*)d_in[11];
    const float* W_c   = (const float*)d_in[12];
    const float* b_c   = (const float*)d_in[13];
    const int*   lens  = (const int*)d_in[14];

    float* out_pred = (float*)d_out;
    float* out_caps = out_pred + (size_t)BS * STEPS * VOCAB;
    float* out_dec  = out_caps + (size_t)BS * T * WV;
    float* out_sidx = out_dec + BS;

    char* w = (char*)d_ws;
    size_t off = 0;
    auto take = [&](size_t bytes) -> char* {
        char* p = w + off;
        off += (bytes + 255) & ~(size_t)255;
        return p;
    };
    int*     sidx = (int*)take(BS * 4);
    int*     dlen = (int*)take(BS * 4);
    float*   Wc   = (float*)take((size_t)G4 * WV * 4);
    float*   bc   = (float*)take(G4 * 4);
    float*   h_st = (float*)take((size_t)BS * H * 4);
    float*   c_st = (float*)take((size_t)BS * H * 4);
    __half2* wT   = (__half2*)take((size_t)(H / 2) * G4 * 4);

    size_t rem = (ws_size > off) ? (ws_size - off) : 0;
    size_t per_step = (size_t)BS * G4 * 4 + (size_t)BS * H * 2 + 1024;
    int C = (int)(rem / per_step);
    if (C < 1) C = 1;
    if (C > STEPS) C = STEPS;
    float*  xg  = (float*)take((size_t)BS * C * G4 * 4);
    __half* hck = (__half*)take((size_t)BS * C * H * 2);

    // allow 138 KB dynamic LDS for the recurrent kernel (host-side, capture-safe)
    (void)hipFuncSetAttribute((const void*)k_lstm,
                              hipFuncAttributeMaxDynamicSharedMemorySize, LSTM_SMEM);

    k_sort<<<1, 256, 0, stream>>>(lens, sidx, dlen, out_dec, out_sidx);
    k_gather<<<BS, 256, 0, stream>>>(caps, sidx, out_caps);
    k_wcomb<<<G4 * WV / 256, 256, 0, stream>>>(w_ih, W_emb, Wc);
    k_bcomb<<<G4 / 256, 256, 0, stream>>>(w_ih, b_ih, b_hh, b_emb, bc);
    k_packw<<<(H / 2) * G4 / 256, 256, 0, stream>>>(w_hh, wT);
    k_inithc<<<BS, 256, 0, stream>>>(enc, sidx, W_h, b_h, W_c, b_c, h_st, c_st);

    for (int t0 = 0; t0 < STEPS; t0 += C) {
        int Cc = STEPS - t0; if (Cc > C) Cc = C;
        dim3 g((Cc + 15) / 16, BS);
        k_xg<<<g, 256, 0, stream>>>(out_caps, Wc, bc, dlen, xg, t0, Cc);
        k_lstm<<<BS, 512, LSTM_SMEM, stream>>>(wT, xg, dlen, h_st, c_st, hck, t0, Cc);
        k_logits<<<g, 256, 0, stream>>>(hck, W_out, b_out, dlen, out_pred, t0, Cc);
    }
}